// Round 1
// baseline (304.942 us; speedup 1.0000x reference)
//
#include <hip/hip_runtime.h>
#include <cstdint>
#include <cstddef>

#define BB 4
#define CC 19
#define HH 512
#define WW 1024
#define HW (HH*WW)          // 524288 = 2^19
#define HW4 (HW/4)          // 131072 = 2^17
#define BHW (BB*HW)
#define KTOP 256
#define EPSF 1e-6f
#define NB1 8192
#define SEG 128
#define LOGC 2.9444389791664403f   // ln(19)

__device__ __forceinline__ unsigned int sortable(float x) {
    unsigned int u = __float_as_uint(x);
    return (u & 0x80000000u) ? ~u : (u | 0x80000000u);
}

// ---------------- Kernel 1: per-pixel entropy (raw sum) + argmax ----------------
__global__ __launch_bounds__(256) void k_ent(const float4* __restrict__ logit,
                                             float4* __restrict__ ent,
                                             uchar4* __restrict__ pred) {
    int idx = blockIdx.x * 256 + threadIdx.x;     // over BHW/4
    int b = idx >> 17;
    int q = idx & (HW4 - 1);
    const float4* base = logit + (size_t)b * CC * HW4 + q;
    float e0 = 0.f, e1 = 0.f, e2 = 0.f, e3 = 0.f;
    float m0 = -1.f, m1 = -1.f, m2 = -1.f, m3 = -1.f;
    int a0 = 0, a1 = 0, a2 = 0, a3 = 0;
#pragma unroll
    for (int c = 0; c < CC; ++c) {
        float4 p = base[(size_t)c * HW4];
        e0 -= p.x * __logf(p.x + EPSF); if (p.x > m0) { m0 = p.x; a0 = c; }
        e1 -= p.y * __logf(p.y + EPSF); if (p.y > m1) { m1 = p.y; a1 = c; }
        e2 -= p.z * __logf(p.z + EPSF); if (p.z > m2) { m2 = p.z; a2 = c; }
        e3 -= p.w * __logf(p.w + EPSF); if (p.w > m3) { m3 = p.w; a3 = c; }
    }
    ent[idx] = make_float4(e0, e1, e2, e3);
    pred[idx] = make_uchar4((unsigned char)a0, (unsigned char)a1,
                            (unsigned char)a2, (unsigned char)a3);
}

// ---------------- Kernel 2: 3x3 region uncertainty * impurity ----------------
__global__ __launch_bounds__(256) void k_score(const float* __restrict__ ent,
                                               const unsigned char* __restrict__ pred,
                                               float* __restrict__ score) {
    int idx = blockIdx.x * 256 + threadIdx.x;     // over BHW
    int b = idx >> 19;
    int hw = idx & (HW - 1);
    int h = hw >> 10;
    int w = hw & (WW - 1);
    const float* eb = ent + (size_t)b * HW;
    const unsigned char* pb = pred + (size_t)b * HW;

    float es = 0.f;
    int cls[9];
    int nv = 0;
#pragma unroll
    for (int i = 0; i < 9; ++i) {
        int dh = i / 3 - 1, dw = i % 3 - 1;
        int hh = h + dh, ww = w + dw;
        bool ok = (hh >= 0) & (hh < HH) & (ww >= 0) & (ww < WW);
        int o = ok ? ((hh << 10) | ww) : 0;
        float e = ok ? eb[o] : 0.f;
        es += e;
        cls[i] = ok ? (int)pb[o] : 255;
        nv += ok ? 1 : 0;
    }
    float inv = 1.f / (float)nv;
    float imp = 0.f;
#pragma unroll
    for (int i = 0; i < 9; ++i) {
        if (cls[i] == 255) continue;
        int cnt = 0;
        bool first = true;
#pragma unroll
        for (int j = 0; j < 9; ++j) {
            cnt += (cls[j] == cls[i]) ? 1 : 0;
            if (j < i && cls[j] == cls[i]) first = false;
        }
        if (first) {
            float d = (float)cnt * inv;
            imp -= d * __logf(d + EPSF);
        }
    }
    float ru = es * (1.f / (9.f * LOGC));
    float ri = imp * (1.f / LOGC);
    score[idx] = ru * ri;
}

// ---------------- Kernel 3: pass-1 13-bit histogram (LDS aggregated) ----------------
__global__ __launch_bounds__(256) void k_hist1(const float* __restrict__ score,
                                               unsigned int* __restrict__ hist1) {
    __shared__ unsigned int lh[NB1];
    int b = blockIdx.x / SEG;
    int seg = blockIdx.x % SEG;
    for (int i = threadIdx.x; i < NB1; i += 256) lh[i] = 0;
    __syncthreads();
    const float4* p = (const float4*)(score + (size_t)b * HW + (size_t)seg * (HW / SEG));
    for (int i = threadIdx.x; i < (HW / SEG) / 4; i += 256) {
        float4 v = p[i];
        atomicAdd(&lh[sortable(v.x) >> 19], 1u);
        atomicAdd(&lh[sortable(v.y) >> 19], 1u);
        atomicAdd(&lh[sortable(v.z) >> 19], 1u);
        atomicAdd(&lh[sortable(v.w) >> 19], 1u);
    }
    __syncthreads();
    unsigned int* hb = hist1 + (size_t)b * NB1;
    for (int i = threadIdx.x; i < NB1; i += 256) {
        unsigned int c = lh[i];
        if (c) atomicAdd(&hb[i], c);
    }
}

// ---------------- Generic 8192-bin top-down scan ----------------
__global__ __launch_bounds__(256) void k_scan(const unsigned int* __restrict__ hist,
                                              const int* __restrict__ rem_in,
                                              unsigned int* __restrict__ T_out,
                                              int* __restrict__ r_out) {
    int b = blockIdx.x;
    const unsigned int* hb = hist + (size_t)b * NB1;
    __shared__ unsigned int csum[256];
    int t = threadIdx.x;
    unsigned int s = 0;
    for (int i = 0; i < 32; ++i) s += hb[t * 32 + i];
    csum[t] = s;
    __syncthreads();
    if (t == 0) {
        int rem = rem_in ? rem_in[b] : KTOP;
        int chunk = 255;
        for (; chunk > 0; --chunk) {
            if ((int)csum[chunk] >= rem) break;
            rem -= (int)csum[chunk];
        }
        int bin = chunk * 32 + 31;
        for (; bin > chunk * 32; --bin) {
            unsigned int c = hb[bin];
            if ((int)c >= rem) break;
            rem -= (int)c;
        }
        T_out[b] = (unsigned int)bin;
        r_out[b] = rem;
    }
}

// ---------------- pass-2: refine next 13 bits ----------------
__global__ __launch_bounds__(256) void k_hist2(const float* __restrict__ score,
                                               const unsigned int* __restrict__ T1,
                                               unsigned int* __restrict__ hist2) {
    int idx = blockIdx.x * 256 + threadIdx.x;
    int b = idx >> 19;
    unsigned int key = sortable(score[idx]);
    if ((key >> 19) == T1[b])
        atomicAdd(&hist2[(size_t)b * NB1 + ((key >> 6) & 0x1FFFu)], 1u);
}

// ---------------- pass-3: refine low 6 bits ----------------
__global__ __launch_bounds__(256) void k_hist3(const float* __restrict__ score,
                                               const unsigned int* __restrict__ T1,
                                               const unsigned int* __restrict__ T2,
                                               unsigned int* __restrict__ hist3) {
    int idx = blockIdx.x * 256 + threadIdx.x;
    int b = idx >> 19;
    unsigned int key = sortable(score[idx]);
    if ((key >> 19) == T1[b] && ((key >> 6) & 0x1FFFu) == T2[b])
        atomicAdd(&hist3[b * 64 + (key & 63u)], 1u);
}

// ---------------- scan-3: exact key + tie contribution ----------------
__global__ void k_scan3(const unsigned int* __restrict__ hist3,
                        const unsigned int* __restrict__ T1,
                        const unsigned int* __restrict__ T2,
                        const int* __restrict__ r2,
                        unsigned int* __restrict__ Kthr,
                        float* __restrict__ out) {
    int b = blockIdx.x;
    if (threadIdx.x == 0) {
        const unsigned int* hb = hist3 + b * 64;
        int rem = r2[b];
        int bin = 63;
        for (; bin > 0; --bin) {
            unsigned int c = hb[bin];
            if ((int)c >= rem) break;
            rem -= (int)c;
        }
        unsigned int K = (T1[b] << 19) | (T2[b] << 6) | (unsigned int)bin;
        unsigned int u = (K & 0x80000000u) ? (K & 0x7FFFFFFFu) : ~K;
        float thr = __uint_as_float(u);
        Kthr[b] = K;
        atomicAdd(&out[b], thr * (float)rem);
    }
}

// ---------------- final: sum all strictly above threshold ----------------
__global__ __launch_bounds__(256) void k_sum(const float* __restrict__ score,
                                             const unsigned int* __restrict__ Kthr,
                                             float* __restrict__ out) {
    int idx = blockIdx.x * 256 + threadIdx.x;
    int b = idx >> 19;
    float v = score[idx];
    unsigned int key = sortable(v);
    if (key > Kthr[b]) atomicAdd(&out[b], v);
}

extern "C" void kernel_launch(void* const* d_in, const int* in_sizes, int n_in,
                              void* d_out, int out_size, void* d_ws, size_t ws_size,
                              hipStream_t stream) {
    const float* logit = (const float*)d_in[0];
    float* out = (float*)d_out;
    char* ws = (char*)d_ws;

    // workspace layout (bytes)
    float*         ent   = (float*)(ws);                           // 8,388,608
    unsigned char* pred  = (unsigned char*)(ws + 8388608);         // 2,097,152
    float*         score = (float*)(ws + 10485760);                // 8,388,608
    unsigned int*  hist1 = (unsigned int*)(ws + 18874368);         // 131,072
    unsigned int*  hist2 = (unsigned int*)(ws + 19005440);         // 131,072
    unsigned int*  hist3 = (unsigned int*)(ws + 19136512);         // 1,024
    char*          scal  = ws + 19137536;
    unsigned int*  T1    = (unsigned int*)(scal);
    int*           r1    = (int*)(scal + 16);
    unsigned int*  T2    = (unsigned int*)(scal + 32);
    int*           r2    = (int*)(scal + 48);
    unsigned int*  Kthr  = (unsigned int*)(scal + 64);

    // zero histograms + scalars + output (ws is poisoned 0xAA before each call)
    hipMemsetAsync(ws + 18874368, 0, 263296, stream);
    hipMemsetAsync(d_out, 0, (size_t)out_size * sizeof(float), stream);

    k_ent<<<BHW / 4 / 256, 256, 0, stream>>>((const float4*)logit, (float4*)ent, (uchar4*)pred);
    k_score<<<BHW / 256, 256, 0, stream>>>(ent, pred, score);
    k_hist1<<<BB * SEG, 256, 0, stream>>>(score, hist1);
    k_scan<<<BB, 256, 0, stream>>>(hist1, nullptr, T1, r1);
    k_hist2<<<BHW / 256, 256, 0, stream>>>(score, T1, hist2);
    k_scan<<<BB, 256, 0, stream>>>(hist2, r1, T2, r2);
    k_hist3<<<BHW / 256, 256, 0, stream>>>(score, T1, T2, hist3);
    k_scan3<<<BB, 64, 0, stream>>>(hist3, T1, T2, r2, Kthr, out);
    k_sum<<<BHW / 256, 256, 0, stream>>>(score, Kthr, out);
}

// Round 2
// 294.543 us; speedup vs baseline: 1.0353x; 1.0353x over previous
//
#include <hip/hip_runtime.h>
#include <cstdint>
#include <cstddef>

#define BB 4
#define CC 19
#define HH 512
#define WW 1024
#define HW (HH*WW)          // 524288 = 2^19
#define HW4 (HW/4)          // 131072 = 2^17
#define BHW (BB*HW)
#define KTOP 256
#define EPSF 1e-6f
#define NB1 8192
#define SEG 128
#define LOGC 2.9444389791664403f   // ln(19)

__device__ __forceinline__ unsigned int sortable(float x) {
    unsigned int u = __float_as_uint(x);
    return (u & 0x80000000u) ? ~u : (u | 0x80000000u);
}
__device__ __forceinline__ float unsortable(unsigned int K) {
    unsigned int u = (K & 0x80000000u) ? (K & 0x7FFFFFFFu) : ~K;
    return __uint_as_float(u);
}

// ---------------- Kernel 1: per-pixel entropy (raw sum) + argmax + zero-init ----------------
__global__ __launch_bounds__(256) void k_ent(const float4* __restrict__ logit,
                                             float4* __restrict__ ent,
                                             uchar4* __restrict__ pred,
                                             unsigned int* __restrict__ histz) {
    int idx = blockIdx.x * 256 + threadIdx.x;     // over BHW/4
    if (idx < 65536) histz[idx] = 0;              // zero hist1+hist2 (contiguous)
    int b = idx >> 17;
    int q = idx & (HW4 - 1);
    const float4* base = logit + (size_t)b * CC * HW4 + q;
    float e0 = 0.f, e1 = 0.f, e2 = 0.f, e3 = 0.f;
    float m0 = -1.f, m1 = -1.f, m2 = -1.f, m3 = -1.f;
    int a0 = 0, a1 = 0, a2 = 0, a3 = 0;
#pragma unroll
    for (int c = 0; c < CC; ++c) {
        float4 p = base[(size_t)c * HW4];
        e0 -= p.x * __logf(p.x + EPSF); if (p.x > m0) { m0 = p.x; a0 = c; }
        e1 -= p.y * __logf(p.y + EPSF); if (p.y > m1) { m1 = p.y; a1 = c; }
        e2 -= p.z * __logf(p.z + EPSF); if (p.z > m2) { m2 = p.z; a2 = c; }
        e3 -= p.w * __logf(p.w + EPSF); if (p.w > m3) { m3 = p.w; a3 = c; }
    }
    ent[idx] = make_float4(e0, e1, e2, e3);
    pred[idx] = make_uchar4((unsigned char)a0, (unsigned char)a1,
                            (unsigned char)a2, (unsigned char)a3);
}

// ---------------- Kernel 2: score + fused LDS-aggregated 13-bit histogram ----------------
__global__ __launch_bounds__(256) void k_score_hist(const float* __restrict__ ent,
                                                    const unsigned char* __restrict__ pred,
                                                    float* __restrict__ score,
                                                    unsigned int* __restrict__ hist1) {
    __shared__ unsigned int lh[NB1];
    int b = blockIdx.x >> 7;          // / SEG
    int seg = blockIdx.x & (SEG - 1);
    for (int i = threadIdx.x; i < NB1; i += 256) lh[i] = 0;
    __syncthreads();
    const float* eb = ent + (size_t)b * HW;
    const unsigned char* pb = pred + (size_t)b * HW;
    int base = seg * (HW / SEG);      // 4096 pixels = 4 rows

    for (int it = 0; it < 16; ++it) {
        int hw = base + it * 256 + threadIdx.x;
        int h = hw >> 10;
        int w = hw & (WW - 1);

        float es = 0.f;
        int cls[9];
        int nv = 0;
#pragma unroll
        for (int i = 0; i < 9; ++i) {
            int dh = i / 3 - 1, dw = i % 3 - 1;
            int hh = h + dh, ww = w + dw;
            bool ok = (hh >= 0) & (hh < HH) & (ww >= 0) & (ww < WW);
            int o = ok ? ((hh << 10) | ww) : 0;
            es += ok ? eb[o] : 0.f;
            cls[i] = ok ? (int)pb[o] : 255;
            nv += ok ? 1 : 0;
        }
        float inv = 1.f / (float)nv;
        float imp = 0.f;
#pragma unroll
        for (int i = 0; i < 9; ++i) {
            if (cls[i] == 255) continue;
            int cnt = 0;
            bool first = true;
#pragma unroll
            for (int j = 0; j < 9; ++j) {
                cnt += (cls[j] == cls[i]) ? 1 : 0;
                if (j < i && cls[j] == cls[i]) first = false;
            }
            if (first) {
                float d = (float)cnt * inv;
                imp -= d * __logf(d + EPSF);
            }
        }
        float v = (es * (1.f / (9.f * LOGC))) * (imp * (1.f / LOGC));
        score[(size_t)b * HW + hw] = v;
        atomicAdd(&lh[sortable(v) >> 19], 1u);
    }
    __syncthreads();
    unsigned int* hb = hist1 + (size_t)b * NB1;
    for (int i = threadIdx.x; i < NB1; i += 256) {
        unsigned int c = lh[i];
        if (c) atomicAdd(&hb[i], c);
    }
}

// ---------------- parallel 8192-bin top-down selection helper (256 threads) ----------------
__device__ __forceinline__ void select_bin(const unsigned int* __restrict__ hb,
                                           int rem, int* bin_out, int* rem_out) {
    __shared__ unsigned int cs[256];
    __shared__ unsigned int bs[32];
    __shared__ int s_chunk, s_bin, s_rem;
    int t = threadIdx.x;
    unsigned int s = 0;
    for (int i = 0; i < 32; ++i) s += hb[t * 32 + i];
    cs[t] = s;
    __syncthreads();
    // Hillis-Steele inclusive suffix scan: cs[t] = sum_{j>=t} csum[j]
    for (int d = 1; d < 256; d <<= 1) {
        unsigned int v = (t + d < 256) ? cs[t + d] : 0;
        __syncthreads();
        cs[t] += v;
        __syncthreads();
    }
    unsigned int St = cs[t];
    unsigned int St1 = (t < 255) ? cs[t + 1] : 0;
    if ((int)St >= rem && (t == 255 || (int)St1 < rem)) {
        s_chunk = t;
        s_rem = rem - (int)St1;
    }
    __syncthreads();
    int chunk = s_chunk;
    int rem2 = s_rem;
    if (t < 32) bs[t] = hb[chunk * 32 + t];
    __syncthreads();
    for (int d = 1; d < 32; d <<= 1) {
        unsigned int v = (t < 32 && t + d < 32) ? bs[t + d] : 0;
        __syncthreads();
        if (t < 32) bs[t] += v;
        __syncthreads();
    }
    if (t < 32) {
        unsigned int Sb = bs[t];
        unsigned int Sb1 = (t < 31) ? bs[t + 1] : 0;
        if ((int)Sb >= rem2 && (t == 31 || (int)Sb1 < rem2)) {
            s_bin = chunk * 32 + t;
            s_rem = rem2 - (int)Sb1;
        }
    }
    __syncthreads();
    *bin_out = s_bin;
    *rem_out = s_rem;
}

// ---------------- scan 1: coarse threshold bin ----------------
__global__ __launch_bounds__(256) void k_scan1(const unsigned int* __restrict__ hist1,
                                               unsigned int* __restrict__ T1,
                                               int* __restrict__ r1) {
    int b = blockIdx.x;
    int bin, rem;
    select_bin(hist1 + (size_t)b * NB1, KTOP, &bin, &rem);
    if (threadIdx.x == 0) { T1[b] = (unsigned int)bin; r1[b] = rem; }
}

// ---------------- pass-2: refine bits 18..6 (LDS aggregated) ----------------
__global__ __launch_bounds__(256) void k_hist2(const float4* __restrict__ score,
                                               const unsigned int* __restrict__ T1,
                                               unsigned int* __restrict__ hist2) {
    __shared__ unsigned int lh[NB1];
    int b = blockIdx.x >> 7;
    int seg = blockIdx.x & (SEG - 1);
    for (int i = threadIdx.x; i < NB1; i += 256) lh[i] = 0;
    __syncthreads();
    unsigned int t1 = T1[b];
    const float4* p = score + ((size_t)b * HW + (size_t)seg * (HW / SEG)) / 4;
    for (int i = threadIdx.x; i < (HW / SEG) / 4; i += 256) {
        float4 v = p[i];
        unsigned int k0 = sortable(v.x), k1 = sortable(v.y);
        unsigned int k2 = sortable(v.z), k3 = sortable(v.w);
        if ((k0 >> 19) == t1) atomicAdd(&lh[(k0 >> 6) & 0x1FFFu], 1u);
        if ((k1 >> 19) == t1) atomicAdd(&lh[(k1 >> 6) & 0x1FFFu], 1u);
        if ((k2 >> 19) == t1) atomicAdd(&lh[(k2 >> 6) & 0x1FFFu], 1u);
        if ((k3 >> 19) == t1) atomicAdd(&lh[(k3 >> 6) & 0x1FFFu], 1u);
    }
    __syncthreads();
    unsigned int* hb = hist2 + (size_t)b * NB1;
    for (int i = threadIdx.x; i < NB1; i += 256) {
        unsigned int c = lh[i];
        if (c) atomicAdd(&hb[i], c);
    }
}

// ---------------- scan 2: exact 26-bit threshold + tie contribution ----------------
__global__ __launch_bounds__(256) void k_scan2(const unsigned int* __restrict__ hist2,
                                               const unsigned int* __restrict__ T1,
                                               const int* __restrict__ r1,
                                               unsigned int* __restrict__ Kthr,
                                               float* __restrict__ out) {
    int b = blockIdx.x;
    int bin, rem;
    select_bin(hist2 + (size_t)b * NB1, r1[b], &bin, &rem);
    if (threadIdx.x == 0) {
        unsigned int K = (T1[b] << 19) | ((unsigned int)bin << 6);
        Kthr[b] = K;
        out[b] = unsortable(K) * (float)rem;   // ties approximated by bin lower edge
    }
}

// ---------------- final: sum all strictly above the 26-bit threshold bin ----------------
__global__ __launch_bounds__(256) void k_sum(const float* __restrict__ score,
                                             const unsigned int* __restrict__ Kthr,
                                             float* __restrict__ out) {
    int idx = blockIdx.x * 256 + threadIdx.x;
    int b = idx >> 19;
    float v = score[idx];
    unsigned int key = sortable(v);
    if ((key & ~63u) > Kthr[b]) atomicAdd(&out[b], v);
}

extern "C" void kernel_launch(void* const* d_in, const int* in_sizes, int n_in,
                              void* d_out, int out_size, void* d_ws, size_t ws_size,
                              hipStream_t stream) {
    const float* logit = (const float*)d_in[0];
    float* out = (float*)d_out;
    char* ws = (char*)d_ws;

    // workspace layout (bytes)
    float*         ent   = (float*)(ws);                           // 8,388,608
    unsigned char* pred  = (unsigned char*)(ws + 8388608);         // 2,097,152
    float*         score = (float*)(ws + 10485760);                // 8,388,608
    unsigned int*  hist1 = (unsigned int*)(ws + 18874368);         // 131,072
    unsigned int*  hist2 = (unsigned int*)(ws + 19005440);         // 131,072 (contiguous after hist1)
    char*          scal  = ws + 19136512;
    unsigned int*  T1    = (unsigned int*)(scal);
    int*           r1    = (int*)(scal + 16);
    unsigned int*  Kthr  = (unsigned int*)(scal + 32);

    k_ent<<<BHW / 4 / 256, 256, 0, stream>>>((const float4*)logit, (float4*)ent,
                                             (uchar4*)pred, hist1 /* zeroes hist1+hist2 */);
    k_score_hist<<<BB * SEG, 256, 0, stream>>>(ent, pred, score, hist1);
    k_scan1<<<BB, 256, 0, stream>>>(hist1, T1, r1);
    k_hist2<<<BB * SEG, 256, 0, stream>>>((const float4*)score, T1, hist2);
    k_scan2<<<BB, 256, 0, stream>>>(hist2, T1, r1, Kthr, out);
    k_sum<<<BHW / 256, 256, 0, stream>>>(score, Kthr, out);
}